// Round 9
// baseline (335.067 us; speedup 1.0000x reference)
//
#include <hip/hip_runtime.h>

typedef unsigned int u32;
typedef unsigned short u16;
typedef float f32x16 __attribute__((ext_vector_type(16)));
typedef __bf16 bf16x8 __attribute__((ext_vector_type(8)));
union BF8 { u32 w[4]; bf16x8 v; };

// ---- diagnostic amplification factors (divide row dur_us by these) ----
#define REP_P 16
#define REP_A 8
#define REP_C 16

#define DEVI static __device__ __forceinline__
DEVI u32 pk_bf16(float lo, float hi) {
  u32 r;
  asm("v_cvt_pk_bf16_f32 %0, %1, %2" : "=v"(r) : "v"(lo), "v"(hi));
  return r;
}
DEVI u16 bf1(float x) { return (u16)(pk_bf16(x, 0.0f) & 0xffffu); }

// ---- workspace byte offsets ----
#define WB_WREP  0        // 27*32*64 bf16 = 110592
#define WB_QS    131072   // 8192*16 bf16
#define WB_K     393216   // 8192*16 bf16
#define WB_VTS   655360   // 256 tiles * 16 ct * 32 keys bf16 = 262144 B
#define WB_FUS   917504   // 8192*64 bf16 = 1 MB: [n][0..31]=x, [n][32..63]=ctx (ends 1966080)

// =============== K1: qkv (in-block pooling + inline BN fold) + wrep repack ===============
__global__ __launch_bounds__(512) void k_prep(
    const float* __restrict__ x,
    const float* __restrict__ wq1, const float* __restrict__ sq1, const float* __restrict__ bq1,
    const float* __restrict__ wq2, const float* __restrict__ sq2, const float* __restrict__ bq2,
    const float* __restrict__ wk1, const float* __restrict__ sk1, const float* __restrict__ bk1,
    const float* __restrict__ wk2, const float* __restrict__ sk2, const float* __restrict__ bk2,
    const float* __restrict__ wv,  const float* __restrict__ sv,  const float* __restrict__ bv,
    const float* __restrict__ wbot, const float* __restrict__ sbot,
    u16* __restrict__ qs, u16* __restrict__ kbm, u16* __restrict__ vts,
    u16* __restrict__ fus, u16* __restrict__ wrep) {
  __shared__ float SH[1664];
  const int tid = threadIdx.x;
  const int bid = blockIdx.x;
  const float* xl = x;
  const float* wbl = wbot;
#pragma clang loop unroll(disable)
  for (int rep = 0; rep < REP_P; ++rep) {
    asm volatile("" : "+v"(xl), "+v"(wbl));   // defeat cross-rep hoisting
    if (bid >= 256) {
      const int rb = bid - 256;
#pragma unroll
      for (int e = 0; e < 8; ++e) {
        const int idx = rb * 4096 + tid * 8 + e;
        if (idx < 55296) {
          const int tap = idx >> 11, rem = idx & 2047, o = rem >> 6, i = rem & 63;
          wrep[idx] = bf1(wbl[(o * 64 + i) * 27 + tap] * sbot[o]);
        }
      }
      continue;
    }
    const int n0 = bid << 5;
    const int d = n0 >> 9;
    // phase A: per-d channel means
    {
      const int c = tid >> 4, part = tid & 15;
      const float4* xp = (const float4*)(xl + (c << 13) + (d << 9));
      float s = 0.f;
#pragma unroll
      for (int i = 0; i < 8; ++i) {
        const float4 v4 = xp[part + (i << 4)];
        s += v4.x + v4.y + v4.z + v4.w;
      }
      SH[1088 + (c << 4) + part] = s;
    }
    __syncthreads();
    if (tid < 32) {
      float s = 0.f;
#pragma unroll
      for (int j = 0; j < 16; ++j) s += SH[1088 + (tid << 4) + j];
      SH[1600 + tid] = s * (1.0f / 512.0f);
    }
    __syncthreads();
    const int nl = tid & 31, g = tid >> 5;
    const int n = n0 + nl;
    {
      float xr[32], xgv[32];
#pragma unroll
      for (int c = 0; c < 32; ++c) xr[c] = xl[(c << 13) + n];
#pragma unroll
      for (int c = 0; c < 32; ++c) xgv[c] = SH[1600 + c];

      const float4* wq1f = (const float4*)wq1;
      const float4* wk1f = (const float4*)wk1;
      const float4* wvf  = (const float4*)wv;
      float dq = 0.f, dk = 0.f, dv = 0.f;
#pragma unroll
      for (int c4 = 0; c4 < 8; ++c4) {
        const float4 wa = wq1f[g * 8 + c4];
        dq += wa.x * xr[4*c4+0] + wa.y * xr[4*c4+1] + wa.z * xr[4*c4+2] + wa.w * xr[4*c4+3];
      }
#pragma unroll
      for (int c4 = 0; c4 < 8; ++c4) {
        const float4 ka = wk1f[g * 16 + c4];
        dk += ka.x * xgv[4*c4+0] + ka.y * xgv[4*c4+1] + ka.z * xgv[4*c4+2] + ka.w * xgv[4*c4+3];
        const float4 va = wvf[g * 16 + c4];
        dv += va.x * xgv[4*c4+0] + va.y * xgv[4*c4+1] + va.z * xgv[4*c4+2] + va.w * xgv[4*c4+3];
      }
#pragma unroll
      for (int c4 = 0; c4 < 8; ++c4) {
        const float4 ka = wk1f[g * 16 + 8 + c4];
        dk += ka.x * xr[4*c4+0] + ka.y * xr[4*c4+1] + ka.z * xr[4*c4+2] + ka.w * xr[4*c4+3];
        const float4 va = wvf[g * 16 + 8 + c4];
        dv += va.x * xr[4*c4+0] + va.y * xr[4*c4+1] + va.z * xr[4*c4+2] + va.w * xr[4*c4+3];
      }
      const float hq = fmaxf(dq * sq1[g] + bq1[g], 0.f);
      const float hk = fmaxf(dk * sk1[g] + bk1[g], 0.f);
      const float hv = fmaxf(dv * sv[g] + bv[g], 0.f);
      SH[nl * 17 + g] = hq;
      SH[544 + nl * 17 + g] = hk;
      vts[(bid << 9) + (g << 5) + nl] = bf1(hv);
      const int c0 = g << 1;
      *(u32*)(fus + (n << 6) + c0) = pk_bf16(xr[c0], xr[c0 + 1]);
    }
    __syncthreads();
    if (tid < 256) {
      const int nl2 = tid & 31, g2 = tid >> 5;
      const int n2 = n0 + nl2;
      const int r0 = 2 * g2, r1 = r0 + 1;
      float eq0 = 0.f, eq1 = 0.f, ek0 = 0.f, ek1 = 0.f;
#pragma unroll
      for (int j = 0; j < 16; ++j) {
        const float hq = SH[nl2 * 17 + j], hk = SH[544 + nl2 * 17 + j];
        eq0 += wq2[r0 * 16 + j] * hq;
        eq1 += wq2[r1 * 16 + j] * hq;
        ek0 += wk2[r0 * 16 + j] * hk;
        ek1 += wk2[r1 * 16 + j] * hk;
      }
      const float SC = 0.36067376022224085f;
      const float q0 = fmaxf(eq0 * (sq2[r0] * SC) + bq2[r0] * SC, 0.f);
      const float q1 = fmaxf(eq1 * (sq2[r1] * SC) + bq2[r1] * SC, 0.f);
      const float k0 = fmaxf(ek0 * sk2[r0] + bk2[r0], 0.f);
      const float k1 = fmaxf(ek1 * sk2[r1] + bk2[r1], 0.f);
      *(u32*)(qs  + (n2 << 4) + r0) = pk_bf16(q0, q1);
      *(u32*)(kbm + (n2 << 4) + r0) = pk_bf16(k0, k1);
    }
    __syncthreads();   // separate rep's SH reads from next rep's writes
  }
}

// =============== K2: flash attention (x REP_A for diagnostics) ===============
__global__ __launch_bounds__(1024) void k_attn(
    const u16* __restrict__ qs, const u16* __restrict__ kbm, const u16* __restrict__ vts,
    const float* __restrict__ wo, const float* __restrict__ so, const float* __restrict__ bo,
    u16* __restrict__ fus) {
  __shared__ float R[16][32][17];
  const int tid = threadIdx.x;
  const int w = tid >> 6, lane = tid & 63;
  const int l31 = lane & 31, h = lane >> 5;
  const int qb = blockIdx.x;

  const bf16x8 qf = *(const bf16x8*)(qs + (((qb << 5) + l31) << 4) + (h << 3));
  const u16* kl = kbm;
  const u16* vl = vts;
#pragma clang loop unroll(disable)
  for (int rep = 0; rep < REP_A; ++rep) {
    asm volatile("" : "+v"(kl), "+v"(vl));   // defeat cross-rep hoisting
    __syncthreads();                          // separate from prev rep's Rf reads
    f32x16 acc_a, acc_b, z;
#pragma unroll
    for (int i = 0; i < 16; ++i) { acc_a[i] = 0.f; acc_b[i] = 0.f; z[i] = 0.f; }

    const u32 fill = (l31 == 16) ? 0x3F803F80u : 0u;
    const int kb0 = w << 9;
    const int t0 = w << 4;
    const bool vlane = (l31 < 16);
    const u16* vbase = vl + (l31 << 5) + (h << 3);

    bf16x8 kf_c = *(const bf16x8*)(kl + ((kb0 + l31) << 4) + (h << 3));
    BF8 V1c, V2c;
#pragma unroll
    for (int j2 = 0; j2 < 4; ++j2) { V1c.w[j2] = fill; V2c.w[j2] = fill; }
    if (vlane) {
      V1c.v = *(const bf16x8*)(vbase + (t0 << 9));
      V2c.v = *(const bf16x8*)(vbase + (t0 << 9) + 16);
    }

#pragma unroll
    for (int t = 0; t < 16; ++t) {
      const bf16x8 kf = kf_c;
      const BF8 V1 = V1c, V2 = V2c;
      if (t < 15) {
        const int kbn = kb0 + ((t + 1) << 5);
        kf_c = *(const bf16x8*)(kl + ((kbn + l31) << 4) + (h << 3));
        if (vlane) {
          const u16* vp = vbase + ((t0 + t + 1) << 9);
          V1c.v = *(const bf16x8*)vp;
          V2c.v = *(const bf16x8*)(vp + 16);
        }
      }
      const f32x16 st = __builtin_amdgcn_mfma_f32_32x32x16_bf16(kf, qf, z, 0, 0, 0);
      float pe[16];
#pragma unroll
      for (int r = 0; r < 16; ++r) pe[r] = __builtin_amdgcn_exp2f(st[r]);
      u32 a0 = pk_bf16(pe[0],  pe[1]),  a1 = pk_bf16(pe[2],  pe[3]);
      u32 a2 = pk_bf16(pe[4],  pe[5]),  a3 = pk_bf16(pe[6],  pe[7]);
      u32 b0 = pk_bf16(pe[8],  pe[9]),  b1 = pk_bf16(pe[10], pe[11]);
      u32 b2 = pk_bf16(pe[12], pe[13]), b3 = pk_bf16(pe[14], pe[15]);
      asm("v_permlane32_swap_b32 %0, %1" : "+v"(a0), "+v"(a2));
      asm("v_permlane32_swap_b32 %0, %1" : "+v"(a1), "+v"(a3));
      asm("v_permlane32_swap_b32 %0, %1" : "+v"(b0), "+v"(b2));
      asm("v_permlane32_swap_b32 %0, %1" : "+v"(b1), "+v"(b3));
      BF8 A1, A2;
      A1.w[0] = a0; A1.w[1] = a1; A1.w[2] = a2; A1.w[3] = a3;
      A2.w[0] = b0; A2.w[1] = b1; A2.w[2] = b2; A2.w[3] = b3;
      __builtin_amdgcn_s_setprio(1);
      acc_a = __builtin_amdgcn_mfma_f32_32x32x16_bf16(A1.v, V1.v, acc_a, 0, 0, 0);
      acc_b = __builtin_amdgcn_mfma_f32_32x32x16_bf16(A2.v, V2.v, acc_b, 0, 0, 0);
      __builtin_amdgcn_s_setprio(0);
    }
    if (l31 < 17) {
#pragma unroll
      for (int r = 0; r < 16; ++r) {
        const int row = (r & 3) + ((r >> 2) << 3) + (h << 2);
        R[w][row][l31] = acc_a[r] + acc_b[r];
      }
    }
    __syncthreads();
    float* Rf = &R[0][0][0];
    if (tid < 544) {
      float s0 = 0.f;
#pragma unroll
      for (int w2 = 0; w2 < 16; ++w2) s0 += Rf[w2 * 544 + tid];
      Rf[tid] = s0;
    }
    __syncthreads();
    if (tid < 512) {
      const int row = tid >> 4;
      const int o0 = (tid & 15) << 1, o1 = o0 + 1;
      const float inv = 1.0f / Rf[row * 17 + 16];
      float d0 = 0.f, d1 = 0.f;
#pragma unroll
      for (int c = 0; c < 16; ++c) {
        const float cv = Rf[row * 17 + c];
        d0 += wo[o0 * 16 + c] * cv;
        d1 += wo[o1 * 16 + c] * cv;
      }
      const float y0 = fmaxf(bo[o0] + so[o0] * d0 * inv, 0.f);
      const float y1 = fmaxf(bo[o1] + so[o1] * d1 * inv, 0.f);
      *(u32*)(fus + (((qb << 5) + row) << 6) + 32 + o0) = pk_bf16(y0, y1);
    }
  }
}

// =============== K3: 3x3x3 conv (x REP_C for diagnostics) ===============
__global__ __launch_bounds__(512) void k_conv(
    const u16* __restrict__ fus, const u16* __restrict__ wrep,
    const float* __restrict__ bbot, float* __restrict__ out) {
  __shared__ float R8[8][1024];
  const int tid = threadIdx.x;
  const int wv = tid >> 6, lane = tid & 63;
  const int l31 = lane & 31, h = lane >> 5;
  const int n0 = blockIdx.x << 5;
  const int dz = n0 >> 9, hy = (n0 >> 5) & 15;
  const u16* fl = fus;
  const u16* wl = wrep;
#pragma clang loop unroll(disable)
  for (int rep = 0; rep < REP_C; ++rep) {
    asm volatile("" : "+v"(fl), "+v"(wl));   // defeat cross-rep hoisting
    __syncthreads();
    f32x16 acc0, acc1;
#pragma unroll
    for (int i = 0; i < 16; ++i) { acc0[i] = 0.f; acc1[i] = 0.f; }
    const int ulo = (wv * 54) >> 3, uhi = ((wv + 1) * 54) >> 3;

    const u16* bp_c; const u16* wp_c; bool ok_c;
    {
      const int tap = ulo >> 1, ch = (ulo & 1) << 1;
      const int dd = tap / 9 - 1, dh = (tap / 3) % 3 - 1, dw = tap % 3 - 1;
      ok_c = ((unsigned)(dz + dd) < 16u) & ((unsigned)(hy + dh) < 16u) &
             ((unsigned)(l31 + dw) < 32u);
      const int nn = n0 + dd * 512 + dh * 32 + dw + l31;
      bp_c = fl + (nn << 6) + (ch << 4) + (h << 3);
      wp_c = wl + ((tap * 32 + l31) << 6) + (ch << 4) + (h << 3);
    }
    BF8 B0c, B1c;
    B0c.w[0] = B0c.w[1] = B0c.w[2] = B0c.w[3] = 0u;
    B1c.w[0] = B1c.w[1] = B1c.w[2] = B1c.w[3] = 0u;
    if (ok_c) { B0c.v = *(const bf16x8*)bp_c; B1c.v = *(const bf16x8*)(bp_c + 16); }

    for (int u = ulo; u < uhi; ++u) {
      const BF8 B0 = B0c, B1 = B1c;
      const u16* wp = wp_c;
      if (u + 1 < uhi) {
        const int un = u + 1;
        const int tap = un >> 1, ch = (un & 1) << 1;
        const int dd = tap / 9 - 1, dh = (tap / 3) % 3 - 1, dw = tap % 3 - 1;
        const bool ok = ((unsigned)(dz + dd) < 16u) & ((unsigned)(hy + dh) < 16u) &
                        ((unsigned)(l31 + dw) < 32u);
        const int nn = n0 + dd * 512 + dh * 32 + dw + l31;
        const u16* bp = fl + (nn << 6) + (ch << 4) + (h << 3);
        wp_c = wl + ((tap * 32 + l31) << 6) + (ch << 4) + (h << 3);
        B0c.w[0] = B0c.w[1] = B0c.w[2] = B0c.w[3] = 0u;
        B1c.w[0] = B1c.w[1] = B1c.w[2] = B1c.w[3] = 0u;
        if (ok) { B0c.v = *(const bf16x8*)bp; B1c.v = *(const bf16x8*)(bp + 16); }
      }
      const bf16x8 af0 = *(const bf16x8*)wp;
      const bf16x8 af1 = *(const bf16x8*)(wp + 16);
      __builtin_amdgcn_s_setprio(1);
      acc0 = __builtin_amdgcn_mfma_f32_32x32x16_bf16(af0, B0.v, acc0, 0, 0, 0);
      acc1 = __builtin_amdgcn_mfma_f32_32x32x16_bf16(af1, B1.v, acc1, 0, 0, 0);
      __builtin_amdgcn_s_setprio(0);
    }
#pragma unroll
    for (int r = 0; r < 16; ++r) {
      const int row = (r & 3) + ((r >> 2) << 3) + (h << 2);
      R8[wv][(row << 5) + l31] = acc0[r] + acc1[r];
    }
    __syncthreads();
#pragma unroll
    for (int k2 = 0; k2 < 2; ++k2) {
      const int e = tid + (k2 << 9);
      const int row = e >> 5;
      float yv = bbot[row];
#pragma unroll
      for (int w2 = 0; w2 < 8; ++w2) yv += R8[w2][e];
      out[(row << 13) + n0 + (e & 31)] = yv > 0.f ? yv : 0.1f * yv;
    }
  }
}

extern "C" void kernel_launch(void* const* d_in, const int* in_sizes, int n_in,
                              void* d_out, int out_size, void* d_ws, size_t ws_size,
                              hipStream_t stream) {
  const float* x    = (const float*)d_in[0];
  const float* wq1  = (const float*)d_in[1];
  const float* sq1  = (const float*)d_in[2];
  const float* bq1  = (const float*)d_in[3];
  const float* wq2  = (const float*)d_in[4];
  const float* sq2  = (const float*)d_in[5];
  const float* bq2  = (const float*)d_in[6];
  const float* wk1  = (const float*)d_in[7];
  const float* sk1  = (const float*)d_in[8];
  const float* bk1  = (const float*)d_in[9];
  const float* wk2  = (const float*)d_in[10];
  const float* sk2  = (const float*)d_in[11];
  const float* bk2  = (const float*)d_in[12];
  const float* wv   = (const float*)d_in[13];
  const float* sv   = (const float*)d_in[14];
  const float* bv   = (const float*)d_in[15];
  const float* wo   = (const float*)d_in[16];
  const float* so   = (const float*)d_in[17];
  const float* bo   = (const float*)d_in[18];
  const float* wbot = (const float*)d_in[19];
  const float* sbot = (const float*)d_in[20];
  const float* bbot = (const float*)d_in[21];
  (void)in_sizes; (void)n_in; (void)out_size; (void)ws_size;

  char* wsb = (char*)d_ws;
  u16* wrep = (u16*)(wsb + WB_WREP);
  u16* qs   = (u16*)(wsb + WB_QS);
  u16* kbm  = (u16*)(wsb + WB_K);
  u16* vts  = (u16*)(wsb + WB_VTS);
  u16* fus  = (u16*)(wsb + WB_FUS);
  float* out = (float*)d_out;

  k_prep<<<270, 512, 0, stream>>>(x, wq1, sq1, bq1, wq2, sq2, bq2,
                                  wk1, sk1, bk1, wk2, sk2, bk2,
                                  wv, sv, bv, wbot, sbot,
                                  qs, kbm, vts, fus, wrep);
  k_attn<<<256, 1024, 0, stream>>>(qs, kbm, vts, wo, so, bo, fus);
  k_conv<<<256, 512, 0, stream>>>(fus, wrep, bbot, out);
}

// Round 10
// 33.445 us; speedup vs baseline: 10.0183x; 10.0183x over previous
//
#include <hip/hip_runtime.h>

typedef unsigned int u32;
typedef unsigned short u16;
typedef float f32x16 __attribute__((ext_vector_type(16)));
typedef __bf16 bf16x8 __attribute__((ext_vector_type(8)));
union BF8 { u32 w[4]; bf16x8 v; };

#define DEVI static __device__ __forceinline__
DEVI u32 pk_bf16(float lo, float hi) {
  u32 r;
  asm("v_cvt_pk_bf16_f32 %0, %1, %2" : "=v"(r) : "v"(lo), "v"(hi));
  return r;
}
DEVI u16 bf1(float x) { return (u16)(pk_bf16(x, 0.0f) & 0xffffu); }

// ---- workspace byte offsets ----
#define WB_WREP  0        // 27*32*64 bf16 = 110592
#define WB_QS    131072   // 8192*16 bf16
#define WB_K     393216   // 8192*16 bf16
#define WB_VTS   655360   // 256 tiles * 16 ct * 32 keys bf16 = 262144 B
#define WB_FUS   917504   // 8192*64 bf16 = 1 MB: [n][0..31]=x, [n][32..63]=ctx

// SH float offsets for k_prep
#define SX_XT   0      // [32][20] staged x tile (pad 20 for b128-aligned stores)
#define SX_H0   640    // [16][17]
#define SX_H1   912    // [16][17]
#define SX_P8   1184   // [32][8]
#define SX_XG   1440   // [32]
#define SX_DKX  1472   // [16]
#define SX_DVX  1488   // [16]

// =============== K1: qkv + wrep repack ===============
// 512 main blocks x 256 threads (16 n each, 2 blocks/CU) + 27 repack blocks.
__global__ __launch_bounds__(256) void k_prep(
    const float* __restrict__ x,
    const float* __restrict__ wq1, const float* __restrict__ sq1, const float* __restrict__ bq1,
    const float* __restrict__ wq2, const float* __restrict__ sq2, const float* __restrict__ bq2,
    const float* __restrict__ wk1, const float* __restrict__ sk1, const float* __restrict__ bk1,
    const float* __restrict__ wk2, const float* __restrict__ sk2, const float* __restrict__ bk2,
    const float* __restrict__ wv,  const float* __restrict__ sv,  const float* __restrict__ bv,
    const float* __restrict__ wbot, const float* __restrict__ sbot,
    u16* __restrict__ qs, u16* __restrict__ kbm, u16* __restrict__ vts,
    u16* __restrict__ fus, u16* __restrict__ wrep) {
  const int tid = threadIdx.x;
  const int bid = blockIdx.x;
  if (bid >= 512) {
    const int rb = bid - 512;
#pragma unroll
    for (int e = 0; e < 8; ++e) {
      const int idx = rb * 2048 + tid * 8 + e;
      const int tap = idx >> 11, rem = idx & 2047, o = rem >> 6, i = rem & 63;
      wrep[idx] = bf1(wbot[(o * 64 + i) * 27 + tap] * sbot[o]);
    }
    return;
  }
  __shared__ float SH[1504];
  const int n0 = bid << 4;          // 16 n per block
  const int d = bid >> 5;
  // ---- phase A: pool partial sums + stage x tile ----
  {
    const int c = tid >> 3, part = tid & 7;
    const float4* xp = (const float4*)(x + (c << 13) + (d << 9));
    float s = 0.f;
#pragma unroll
    for (int i = 0; i < 16; ++i) {
      const float4 v4 = xp[part + (i << 3)];
      s += v4.x + v4.y + v4.z + v4.w;
    }
    SH[SX_P8 + (c << 3) + part] = s;
    if (tid < 128) {   // stage x[32c][16n] via coalesced float4
      const int cc = tid >> 2, ii = tid & 3;
      const float4 v4 = *(const float4*)(x + (cc << 13) + n0 + (ii << 2));
      *(float4*)(&SH[SX_XT + cc * 20 + (ii << 2)]) = v4;
    }
  }
  __syncthreads();
  if (tid < 32) {
    float s = 0.f;
#pragma unroll
    for (int j = 0; j < 8; ++j) s += SH[SX_P8 + (tid << 3) + j];
    SH[SX_XG + tid] = s * (1.0f / 512.0f);
    // xg-half dots: dk_xg[g], dv_xg[g] (shared by all n of this d)
    const float4* wxf = (tid < 16) ? (const float4*)wk1 : (const float4*)wv;
    const int g = tid & 15;
    float dx = 0.f;
#pragma unroll
    for (int c4 = 0; c4 < 8; ++c4) {
      const float4 wa = wxf[g * 16 + c4];
      dx += wa.x * SH[SX_XG + 4*c4] + wa.y * SH[SX_XG + 4*c4+1] +
            wa.z * SH[SX_XG + 4*c4+2] + wa.w * SH[SX_XG + 4*c4+3];
    }
    SH[(tid < 16 ? SX_DKX : SX_DVX - 16) + tid] = dx;
  }
  __syncthreads();
  // ---- phase B: first-layer projections, 1 output per thread (16 n x 16 g) ----
  const int nl = tid & 15, g = tid >> 4;
  const int n = n0 + nl;
  {
    float xc[32];
#pragma unroll
    for (int c = 0; c < 32; ++c) xc[c] = SH[SX_XT + c * 20 + nl];
    const float4* wq1f = (const float4*)wq1;
    const float4* wk1f = (const float4*)wk1;
    const float4* wvf  = (const float4*)wv;
    float dq = 0.f, dk = SH[SX_DKX + g], dv = SH[SX_DVX + g];
#pragma unroll
    for (int c4 = 0; c4 < 8; ++c4) {
      const float4 wa = wq1f[g * 8 + c4];
      dq += wa.x * xc[4*c4+0] + wa.y * xc[4*c4+1] + wa.z * xc[4*c4+2] + wa.w * xc[4*c4+3];
      const float4 ka = wk1f[g * 16 + 8 + c4];
      dk += ka.x * xc[4*c4+0] + ka.y * xc[4*c4+1] + ka.z * xc[4*c4+2] + ka.w * xc[4*c4+3];
      const float4 va = wvf[g * 16 + 8 + c4];
      dv += va.x * xc[4*c4+0] + va.y * xc[4*c4+1] + va.z * xc[4*c4+2] + va.w * xc[4*c4+3];
    }
    const float hq = fmaxf(dq * sq1[g] + bq1[g], 0.f);
    const float hk = fmaxf(dk * sk1[g] + bk1[g], 0.f);
    const float hv = fmaxf(dv * sv[g] + bv[g], 0.f);
    SH[SX_H0 + nl * 17 + g] = hq;
    SH[SX_H1 + nl * 17 + g] = hk;
    vts[((n >> 5) << 9) + (g << 5) + (n & 31)] = bf1(hv);
    // x channels into fused conv-input buffer (2 ch per thread)
    const int c0 = g << 1;
    *(u32*)(fus + (n << 6) + c0) = pk_bf16(SH[SX_XT + c0 * 20 + nl],
                                           SH[SX_XT + (c0 + 1) * 20 + nl]);
  }
  __syncthreads();
  // ---- phase C: second-layer projections: 16 n x (8 q-pairs + 8 k-pairs) ----
  {
    const int op = tid >> 4;   // 0..7 q-pair, 8..15 k-pair
    const bool isq = (op < 8);
    const int r0 = (op & 7) << 1, r1 = r0 + 1;
    const float* w2 = isq ? wq2 : wk2;
    const float* Hrow = &SH[(isq ? SX_H0 : SX_H1) + nl * 17];
    float e0 = 0.f, e1 = 0.f;
#pragma unroll
    for (int j = 0; j < 16; ++j) {
      const float hv2 = Hrow[j];
      e0 += w2[r0 * 16 + j] * hv2;
      e1 += w2[r1 * 16 + j] * hv2;
    }
    if (isq) {
      const float SC = 0.36067376022224085f;  // CT^-0.5 * log2(e), folded into q
      const float q0 = fmaxf(e0 * (sq2[r0] * SC) + bq2[r0] * SC, 0.f);
      const float q1 = fmaxf(e1 * (sq2[r1] * SC) + bq2[r1] * SC, 0.f);
      *(u32*)(qs + (n << 4) + r0) = pk_bf16(q0, q1);
    } else {
      const float k0 = fmaxf(e0 * sk2[r0] + bk2[r0], 0.f);
      const float k1 = fmaxf(e1 * sk2[r1] + bk2[r1], 0.f);
      *(u32*)(kbm + (n << 4) + r0) = pk_bf16(k0, k1);
    }
  }
}

// =============== K2: flash attention, QK-ahead software pipeline ===============
// 256 blocks x 1024 threads (16 waves, 4/SIMD). Per body: QK(t+1) MFMA first,
// then loads(t+1), then exp2/pack/PV(t) in two interleaved halves.
__global__ __launch_bounds__(1024) void k_attn(
    const u16* __restrict__ qs, const u16* __restrict__ kbm, const u16* __restrict__ vts,
    const float* __restrict__ wo, const float* __restrict__ so, const float* __restrict__ bo,
    u16* __restrict__ fus) {
  __shared__ float R[16][32][17];
  const int tid = threadIdx.x;
  const int w = tid >> 6, lane = tid & 63;
  const int l31 = lane & 31, h = lane >> 5;
  const int qb = blockIdx.x;

  const bf16x8 qf = *(const bf16x8*)(qs + (((qb << 5) + l31) << 4) + (h << 3));
  f32x16 acc_a, acc_b, z;
#pragma unroll
  for (int i = 0; i < 16; ++i) { acc_a[i] = 0.f; acc_b[i] = 0.f; z[i] = 0.f; }

  const u32 fill = (l31 == 16) ? 0x3F803F80u : 0u;  // ones-column: denom rides col 16
  const int kb0 = w << 9;          // 512 keys per wave
  const int t0 = w << 4;           // first tile index
  const bool vlane = (l31 < 16);
  const u16* vbase = vts + (l31 << 5) + (h << 3);
  const u16* krow = kbm + (l31 << 4) + (h << 3);

  // prologue: K(0),V(0); st = QK(0); prefetch K(1)
  bf16x8 kf_c = *(const bf16x8*)(krow + (kb0 << 4));
  BF8 V1c, V2c;
#pragma unroll
  for (int j2 = 0; j2 < 4; ++j2) { V1c.w[j2] = fill; V2c.w[j2] = fill; }
  if (vlane) {
    V1c.v = *(const bf16x8*)(vbase + (t0 << 9));
    V2c.v = *(const bf16x8*)(vbase + (t0 << 9) + 16);
  }
  f32x16 st = __builtin_amdgcn_mfma_f32_32x32x16_bf16(kf_c, qf, z, 0, 0, 0);
  kf_c = *(const bf16x8*)(krow + ((kb0 + 32) << 4));

#pragma unroll
  for (int t = 0; t < 16; ++t) {
    // 1) issue QK(t+1) first — its latency hides under exp2/pack of tile t
    f32x16 st_next;
    if (t < 15) st_next = __builtin_amdgcn_mfma_f32_32x32x16_bf16(kf_c, qf, z, 0, 0, 0);
    const BF8 V1 = V1c, V2 = V2c;
    // 2) issue loads for the next tiles
    if (t < 14) kf_c = *(const bf16x8*)(krow + ((kb0 + ((t + 2) << 5)) << 4));
    if (t < 15 && vlane) {
      const u16* vp = vbase + ((t0 + t + 1) << 9);
      V1c.v = *(const bf16x8*)vp;
      V2c.v = *(const bf16x8*)(vp + 16);
    }
    // 3) half 1: exp2 + pack + PV1
    float pe[16];
#pragma unroll
    for (int r = 0; r < 8; ++r) pe[r] = __builtin_amdgcn_exp2f(st[r]);
    u32 a0 = pk_bf16(pe[0], pe[1]), a1 = pk_bf16(pe[2], pe[3]);
    u32 a2 = pk_bf16(pe[4], pe[5]), a3 = pk_bf16(pe[6], pe[7]);
    asm("v_permlane32_swap_b32 %0, %1" : "+v"(a0), "+v"(a2));
    asm("v_permlane32_swap_b32 %0, %1" : "+v"(a1), "+v"(a3));
    BF8 A1;
    A1.w[0] = a0; A1.w[1] = a1; A1.w[2] = a2; A1.w[3] = a3;
    __builtin_amdgcn_s_setprio(1);
    acc_a = __builtin_amdgcn_mfma_f32_32x32x16_bf16(A1.v, V1.v, acc_a, 0, 0, 0);
    __builtin_amdgcn_s_setprio(0);
    // 4) half 2: exp2 + pack + PV2
#pragma unroll
    for (int r = 8; r < 16; ++r) pe[r] = __builtin_amdgcn_exp2f(st[r]);
    u32 b0 = pk_bf16(pe[8],  pe[9]),  b1 = pk_bf16(pe[10], pe[11]);
    u32 b2 = pk_bf16(pe[12], pe[13]), b3 = pk_bf16(pe[14], pe[15]);
    asm("v_permlane32_swap_b32 %0, %1" : "+v"(b0), "+v"(b2));
    asm("v_permlane32_swap_b32 %0, %1" : "+v"(b1), "+v"(b3));
    BF8 A2;
    A2.w[0] = b0; A2.w[1] = b1; A2.w[2] = b2; A2.w[3] = b3;
    __builtin_amdgcn_s_setprio(1);
    acc_b = __builtin_amdgcn_mfma_f32_32x32x16_bf16(A2.v, V2.v, acc_b, 0, 0, 0);
    __builtin_amdgcn_s_setprio(0);
    if (t < 15) st = st_next;
  }
  if (l31 < 17) {
#pragma unroll
    for (int r = 0; r < 16; ++r) {
      const int row = (r & 3) + ((r >> 2) << 3) + (h << 2);
      R[w][row][l31] = acc_a[r] + acc_b[r];
    }
  }
  __syncthreads();
  float* Rf = &R[0][0][0];
  if (tid < 544) {
    float s0 = 0.f;
#pragma unroll
    for (int w2 = 0; w2 < 16; ++w2) s0 += Rf[w2 * 544 + tid];
    Rf[tid] = s0;
  }
  __syncthreads();
  if (tid < 512) {
    const int row = tid >> 4;
    const int o0 = (tid & 15) << 1, o1 = o0 + 1;
    const float inv = 1.0f / Rf[row * 17 + 16];
    float d0 = 0.f, d1 = 0.f;
#pragma unroll
    for (int c = 0; c < 16; ++c) {
      const float cv = Rf[row * 17 + c];
      d0 += wo[o0 * 16 + c] * cv;
      d1 += wo[o1 * 16 + c] * cv;
    }
    const float y0 = fmaxf(bo[o0] + so[o0] * d0 * inv, 0.f);
    const float y1 = fmaxf(bo[o1] + so[o1] * d1 * inv, 0.f);
    *(u32*)(fus + (((qb << 5) + row) << 6) + 32 + o0) = pk_bf16(y0, y1);
  }
}

// =============== K3: 3x3x3 conv, 54 units over 8 waves + LDS reduce ===============
__global__ __launch_bounds__(512) void k_conv(
    const u16* __restrict__ fus, const u16* __restrict__ wrep,
    const float* __restrict__ bbot, float* __restrict__ out) {
  __shared__ float R8[8][1024];
  const int tid = threadIdx.x;
  const int wv = tid >> 6, lane = tid & 63;
  const int l31 = lane & 31, h = lane >> 5;
  const int n0 = blockIdx.x << 5;
  const int dz = n0 >> 9, hy = (n0 >> 5) & 15;
  f32x16 acc0, acc1;
#pragma unroll
  for (int i = 0; i < 16; ++i) { acc0[i] = 0.f; acc1[i] = 0.f; }
  const int ulo = (wv * 54) >> 3, uhi = ((wv + 1) * 54) >> 3;

  const u16* bp_c; const u16* wp_c; bool ok_c;
  {
    const int tap = ulo >> 1, ch = (ulo & 1) << 1;
    const int dd = tap / 9 - 1, dh = (tap / 3) % 3 - 1, dw = tap % 3 - 1;
    ok_c = ((unsigned)(dz + dd) < 16u) & ((unsigned)(hy + dh) < 16u) &
           ((unsigned)(l31 + dw) < 32u);
    const int nn = n0 + dd * 512 + dh * 32 + dw + l31;
    bp_c = fus + (nn << 6) + (ch << 4) + (h << 3);
    wp_c = wrep + ((tap * 32 + l31) << 6) + (ch << 4) + (h << 3);
  }
  BF8 B0c, B1c;
  B0c.w[0] = B0c.w[1] = B0c.w[2] = B0c.w[3] = 0u;
  B1c.w[0] = B1c.w[1] = B1c.w[2] = B1c.w[3] = 0u;
  if (ok_c) { B0c.v = *(const bf16x8*)bp_c; B1c.v = *(const bf16x8*)(bp_c + 16); }

  for (int u = ulo; u < uhi; ++u) {
    const BF8 B0 = B0c, B1 = B1c;
    const u16* wp = wp_c;
    if (u + 1 < uhi) {
      const int un = u + 1;
      const int tap = un >> 1, ch = (un & 1) << 1;
      const int dd = tap / 9 - 1, dh = (tap / 3) % 3 - 1, dw = tap % 3 - 1;
      const bool ok = ((unsigned)(dz + dd) < 16u) & ((unsigned)(hy + dh) < 16u) &
                      ((unsigned)(l31 + dw) < 32u);
      const int nn = n0 + dd * 512 + dh * 32 + dw + l31;
      const u16* bp = fus + (nn << 6) + (ch << 4) + (h << 3);
      wp_c = wrep + ((tap * 32 + l31) << 6) + (ch << 4) + (h << 3);
      B0c.w[0] = B0c.w[1] = B0c.w[2] = B0c.w[3] = 0u;
      B1c.w[0] = B1c.w[1] = B1c.w[2] = B1c.w[3] = 0u;
      if (ok) { B0c.v = *(const bf16x8*)bp; B1c.v = *(const bf16x8*)(bp + 16); }
    }
    const bf16x8 af0 = *(const bf16x8*)wp;
    const bf16x8 af1 = *(const bf16x8*)(wp + 16);
    __builtin_amdgcn_s_setprio(1);
    acc0 = __builtin_amdgcn_mfma_f32_32x32x16_bf16(af0, B0.v, acc0, 0, 0, 0);
    acc1 = __builtin_amdgcn_mfma_f32_32x32x16_bf16(af1, B1.v, acc1, 0, 0, 0);
    __builtin_amdgcn_s_setprio(0);
  }
#pragma unroll
  for (int r = 0; r < 16; ++r) {
    const int row = (r & 3) + ((r >> 2) << 3) + (h << 2);
    R8[wv][(row << 5) + l31] = acc0[r] + acc1[r];
  }
  __syncthreads();
#pragma unroll
  for (int k2 = 0; k2 < 2; ++k2) {
    const int e = tid + (k2 << 9);
    const int row = e >> 5;
    float yv = bbot[row];
#pragma unroll
    for (int w2 = 0; w2 < 8; ++w2) yv += R8[w2][e];
    out[(row << 13) + n0 + (e & 31)] = yv > 0.f ? yv : 0.1f * yv;
  }
}

extern "C" void kernel_launch(void* const* d_in, const int* in_sizes, int n_in,
                              void* d_out, int out_size, void* d_ws, size_t ws_size,
                              hipStream_t stream) {
  const float* x    = (const float*)d_in[0];
  const float* wq1  = (const float*)d_in[1];
  const float* sq1  = (const float*)d_in[2];
  const float* bq1  = (const float*)d_in[3];
  const float* wq2  = (const float*)d_in[4];
  const float* sq2  = (const float*)d_in[5];
  const float* bq2  = (const float*)d_in[6];
  const float* wk1  = (const float*)d_in[7];
  const float* sk1  = (const float*)d_in[8];
  const float* bk1  = (const float*)d_in[9];
  const float* wk2  = (const float*)d_in[10];
  const float* sk2  = (const float*)d_in[11];
  const float* bk2  = (const float*)d_in[12];
  const float* wv   = (const float*)d_in[13];
  const float* sv   = (const float*)d_in[14];
  const float* bv   = (const float*)d_in[15];
  const float* wo   = (const float*)d_in[16];
  const float* so   = (const float*)d_in[17];
  const float* bo   = (const float*)d_in[18];
  const float* wbot = (const float*)d_in[19];
  const float* sbot = (const float*)d_in[20];
  const float* bbot = (const float*)d_in[21];
  (void)in_sizes; (void)n_in; (void)out_size; (void)ws_size;

  char* wsb = (char*)d_ws;
  u16* wrep = (u16*)(wsb + WB_WREP);
  u16* qs   = (u16*)(wsb + WB_QS);
  u16* kbm  = (u16*)(wsb + WB_K);
  u16* vts  = (u16*)(wsb + WB_VTS);
  u16* fus  = (u16*)(wsb + WB_FUS);
  float* out = (float*)d_out;

  k_prep<<<539, 256, 0, stream>>>(x, wq1, sq1, bq1, wq2, sq2, bq2,
                                  wk1, sk1, bk1, wk2, sk2, bk2,
                                  wv, sv, bv, wbot, sbot,
                                  qs, kbm, vts, fus, wrep);
  k_attn<<<256, 1024, 0, stream>>>(qs, kbm, vts, wo, so, bo, fus);
  k_conv<<<256, 512, 0, stream>>>(fus, wrep, bbot, out);
}